// Round 1
// baseline (414.381 us; speedup 1.0000x reference)
//
#include <hip/hip_runtime.h>

// Problem constants (fixed by the reference)
#define B_TOT 16384
#define N_CAP 32
#define TB    32       // batch rows per block
#define NTH   512      // 8 waves: wave w handles n in [4w, 4w+4)
#define LSTR  516      // u16 stride of per-b logit row (32*16 + 4 pad)

// fp32 -> bf16 (RNE) and back, on raw bits
__device__ __forceinline__ unsigned short f2bf(float f) {
    unsigned int u = __float_as_uint(f);
    unsigned int r = (u + 0x7fffu + ((u >> 16) & 1u)) >> 16;
    return (unsigned short)r;
}
__device__ __forceinline__ float bf2f(unsigned int s) {   // s < 65536
    return __uint_as_float(s << 16);
}

// Thread map: b = tid&31 (batch row in tile), zh = bit5 (z half: [zh*8, zh*8+8)),
// wave w = tid>>6 handles output capsules n = 4w..4w+3.
// W is read via broadcast global loads (wave-uniform addr -> 1 L1/L2 access),
// x from a small XOR-swizzled LDS tile; all reductions are in registers.
__global__ __launch_bounds__(NTH, 4)
void caps_fused(const float* __restrict__ X,     // (B, 16, 8)
                const float* __restrict__ W,     // (32, 16, 8, 16)
                const float* __restrict__ Bias,  // (32, 16, 1)
                float* __restrict__ Out)         // (B, 32, 16)
{
    __shared__ __align__(16) float sX[TB * 128];   // x tile, 16B-block XOR swizzle
    __shared__ unsigned short sL[TB * LSTR];       // logits -> c, bf16
    __shared__ float sBias[512];

    const int t  = threadIdx.x;
    const int b  = t & 31;
    const int zh = (t >> 5) & 1;
    const int w  = t >> 6;
    const long bbase = (long)blockIdx.x * TB;

    // ---- stage X tile (coalesced; swizzle 16B block index with row&7) + bias ----
    {
        const float4* Xg = reinterpret_cast<const float4*>(X + bbase * 128);
        float4* sX4w = reinterpret_cast<float4*>(sX);
        #pragma unroll
        for (int k = 0; k < 2; ++k) {
            const int idx = t + k * NTH;          // 0..1023 float4s
            const int br  = idx >> 5;             // row 0..31
            const int c4  = idx & 31;             // 16B block 0..31
            sX4w[br * 32 + (c4 ^ (br & 7))] = Xg[idx];
        }
        sBias[t] = Bias[t];                        // 512 floats
    }
    __syncthreads();

    const float4* sX4 = reinterpret_cast<const float4*>(sX);
    const int bs   = b & 7;
    const int brow = b * 32;
    const int zoff = zh * 2;

    // acc[z] += sum_i x[b,jj,i] * W[n,jj,i, zh*8+z], z = 0..7
    auto uslice = [&](const float4* Wn4, int jj, float (&acc)[8]) {
        const float4 xa = sX4[brow + ((2 * jj)     ^ bs)];
        const float4 xb = sX4[brow + ((2 * jj + 1) ^ bs)];
        const float xv[8] = {xa.x, xa.y, xa.z, xa.w, xb.x, xb.y, xb.z, xb.w};
        #pragma unroll
        for (int i = 0; i < 8; ++i) {
            const float4 w0 = Wn4[jj * 32 + i * 4 + zoff];       // broadcast load
            const float4 w1 = Wn4[jj * 32 + i * 4 + zoff + 1];
            acc[0] = fmaf(xv[i], w0.x, acc[0]);
            acc[1] = fmaf(xv[i], w0.y, acc[1]);
            acc[2] = fmaf(xv[i], w0.z, acc[2]);
            acc[3] = fmaf(xv[i], w0.w, acc[3]);
            acc[4] = fmaf(xv[i], w1.x, acc[4]);
            acc[5] = fmaf(xv[i], w1.y, acc[5]);
            acc[6] = fmaf(xv[i], w1.z, acc[6]);
            acc[7] = fmaf(xv[i], w1.w, acc[7]);
        }
    };

    // ---------------- pass 1: logits for this wave's n ----------------
    #pragma unroll 1
    for (int q = 0; q < 4; ++q) {
        const int n = w * 4 + q;
        const float4* Wn4 = reinterpret_cast<const float4*>(W + (size_t)n * 2048);

        // stream 1: usum[z] = sum_{j,i} x*W (fp32, no u storage)
        float usum[8] = {0.f,0.f,0.f,0.f,0.f,0.f,0.f,0.f};
        #pragma unroll 1
        for (int jj = 0; jj < 16; ++jj)
            uslice(Wn4, jj, usum);

        // stream 2: u_jj then logit l = (u_jj . usum)/sqrt(16)
        #pragma unroll 1
        for (int jj = 0; jj < 16; ++jj) {
            float u[8] = {0.f,0.f,0.f,0.f,0.f,0.f,0.f,0.f};
            uslice(Wn4, jj, u);
            float p0 = u[0] * usum[0];
            float p1 = u[1] * usum[1];
            p0 = fmaf(u[2], usum[2], p0);
            p1 = fmaf(u[3], usum[3], p1);
            p0 = fmaf(u[4], usum[4], p0);
            p1 = fmaf(u[5], usum[5], p1);
            p0 = fmaf(u[6], usum[6], p0);
            p1 = fmaf(u[7], usum[7], p1);
            float d = p0 + p1;
            d += __shfl_xor(d, 32);               // combine the two z-halves
            if (!zh) sL[b * LSTR + n * 16 + jj] = f2bf(d * 0.25f);
        }
    }
    __syncthreads();

    // ---------------- softmax over n (+ bias), one (b,j) per thread ----------------
    {
        const int sb = t >> 4;      // 0..31
        const int sj = t & 15;
        float l[32];
        #pragma unroll
        for (int n = 0; n < 32; ++n)
            l[n] = bf2f((unsigned int)sL[sb * LSTR + n * 16 + sj]);
        float m = l[0];
        #pragma unroll
        for (int n = 1; n < 32; ++n) m = fmaxf(m, l[n]);
        float Z = 0.f;
        #pragma unroll
        for (int n = 0; n < 32; ++n) { l[n] = __expf(l[n] - m); Z += l[n]; }
        const float inv = 1.0f / Z;
        #pragma unroll
        for (int n = 0; n < 32; ++n)
            sL[sb * LSTR + n * 16 + sj] = f2bf(fmaf(l[n], inv, sBias[n * 16 + sj]));
    }
    __syncthreads();

    // ---------------- pass 2: s[b,n,z] = sum_j c[b,n,j] * u[b,n,j,z] ----------------
    #pragma unroll 1
    for (int q = 0; q < 4; ++q) {
        const int n = w * 4 + q;
        const float4* Wn4 = reinterpret_cast<const float4*>(W + (size_t)n * 2048);
        float s[8] = {0.f,0.f,0.f,0.f,0.f,0.f,0.f,0.f};
        #pragma unroll 1
        for (int jj = 0; jj < 16; ++jj) {
            const float cj = bf2f((unsigned int)sL[b * LSTR + n * 16 + jj]);
            float u[8] = {0.f,0.f,0.f,0.f,0.f,0.f,0.f,0.f};
            uslice(Wn4, jj, u);
            s[0] = fmaf(cj, u[0], s[0]);
            s[1] = fmaf(cj, u[1], s[1]);
            s[2] = fmaf(cj, u[2], s[2]);
            s[3] = fmaf(cj, u[3], s[3]);
            s[4] = fmaf(cj, u[4], s[4]);
            s[5] = fmaf(cj, u[5], s[5]);
            s[6] = fmaf(cj, u[6], s[6]);
            s[7] = fmaf(cj, u[7], s[7]);
        }
        float4* Og = reinterpret_cast<float4*>(
            Out + (size_t)(bbase + b) * 512 + n * 16 + zh * 8);
        Og[0] = make_float4(s[0], s[1], s[2], s[3]);
        Og[1] = make_float4(s[4], s[5], s[6], s[7]);
    }
}

extern "C" void kernel_launch(void* const* d_in, const int* in_sizes, int n_in,
                              void* d_out, int out_size, void* d_ws, size_t ws_size,
                              hipStream_t stream) {
    const float* X  = (const float*)d_in[0];   // (16384, 16, 8) fp32
    const float* W  = (const float*)d_in[1];   // (32, 16, 8, 16) fp32
    const float* Bi = (const float*)d_in[2];   // (32, 16, 1) fp32
    float* Out = (float*)d_out;                // (16384, 32, 16) fp32

    caps_fused<<<B_TOT / TB, NTH, 0, stream>>>(X, W, Bi, Out);
}

// Round 2
// 118.090 us; speedup vs baseline: 3.5090x; 3.5090x over previous
//
#include <hip/hip_runtime.h>

// Problem constants (fixed by the reference)
#define B_TOT 16384
#define TBB   16          // batch rows per block
#define NTH   256         // 4 waves: wave w handles n in [8w, 8w+8)
#define SLS   524         // f32 stride of sL row (16B-aligned, 2-way-max banks)

typedef short bf16x8 __attribute__((ext_vector_type(8)));
typedef float f32x4  __attribute__((ext_vector_type(4)));

__device__ __forceinline__ unsigned int f2bf(float f) {
    unsigned int u = __float_as_uint(f);
    return (u + 0x7fffu + ((u >> 16) & 1u)) >> 16;   // RNE, result < 65536
}

// ---- prepack: W (32,16,8,16) f32 -> A-fragment layout, bf16 ----
// Wp[(n*16+j)*16 + z] (uint4) = bf16{ W[n][j][0..7][z] }  (A[m=z][k=i], lane z)
__global__ void prepack_W(const float* __restrict__ W, uint4* __restrict__ Wp)
{
    const int t  = blockIdx.x * 256 + threadIdx.x;  // 0..8191
    const int z  = t & 15;
    const int nj = t >> 4;
    const float* src = W + (size_t)nj * 128 + z;    // stride 16 over i
    uint4 o;
    o.x = f2bf(src[0])  | (f2bf(src[16])  << 16);
    o.y = f2bf(src[32]) | (f2bf(src[48])  << 16);
    o.z = f2bf(src[64]) | (f2bf(src[80])  << 16);
    o.w = f2bf(src[96]) | (f2bf(src[112]) << 16);
    Wp[t] = o;
}

// Per (n,j): D[z,b] = sum_i W[n,j,i,z] * x[b,j,i] via mfma_f32_16x16x32_bf16.
// A-frag: lane<16 holds W col (k=i=0..7); lanes>=16 garbage-OK (B is zero there).
// B-frag: lane<16 holds x[b=lane][j][0..7]; lanes>=16 zeroed once.
// D: col=lane&15=b, row=(lane>>4)*4+reg=z  [m89-verified mapping].
__global__ __launch_bounds__(NTH, 3)
void caps_mfma(const float* __restrict__ X,     // (B,16,8)
               const uint4*  __restrict__ Wp,   // packed A-frags
               const float* __restrict__ Bias,  // (32,16,1)
               float* __restrict__ Out)         // (B,32,16)
{
    __shared__ __align__(16) float sL[TBB * SLS];  // logits -> c, f32
    __shared__ float sBias[512];

    const int t    = threadIdx.x;
    const int lane = t & 63;
    const int wv   = t >> 6;            // wave 0..3 -> n range
    const int l16  = lane & 15;         // b (and A/B frag lane role)
    const int zg   = lane >> 4;         // z-group 0..3
    const long bb  = (long)blockIdx.x * TBB;

    sBias[t]       = Bias[t];
    sBias[t + 256] = Bias[t + 256];

    // ---- x fragments (held in regs for the whole kernel) ----
    union U8 { bf16x8 v; uint4 q; };
    bf16x8 xf[16];
    {
        U8 z8; z8.q = make_uint4(0u, 0u, 0u, 0u);
        #pragma unroll
        for (int j = 0; j < 16; ++j) xf[j] = z8.v;   // lanes>=16 stay zero
    }
    if (lane < 16) {
        const float* xr = X + (bb + l16) * 128;
        #pragma unroll
        for (int j = 0; j < 16; ++j) {
            float4 a = *reinterpret_cast<const float4*>(xr + j * 8);
            float4 b = *reinterpret_cast<const float4*>(xr + j * 8 + 4);
            U8 p;
            p.q.x = f2bf(a.x) | (f2bf(a.y) << 16);
            p.q.y = f2bf(a.z) | (f2bf(a.w) << 16);
            p.q.z = f2bf(b.x) | (f2bf(b.y) << 16);
            p.q.w = f2bf(b.z) | (f2bf(b.w) << 16);
            xf[j] = p.v;
        }
    }

    const f32x4 zero4 = {0.f, 0.f, 0.f, 0.f};

    // ---------------- pass 1: logits for this wave's 8 n ----------------
    #pragma unroll 1
    for (int q = 0; q < 8; ++q) {
        const int n = wv * 8 + q;
        const uint4* wpn = Wp + n * 256 + l16;        // + j*16, imm offsets

        // usum[b,z] via 4 parallel j-chains of C-accumulating MFMAs
        f32x4 acc[4] = {zero4, zero4, zero4, zero4};
        #pragma unroll
        for (int j = 0; j < 16; ++j) {
            U8 a; a.q = wpn[j * 16];
            acc[j & 3] = __builtin_amdgcn_mfma_f32_16x16x32_bf16(a.v, xf[j], acc[j & 3], 0, 0, 0);
        }
        const f32x4 usum = (acc[0] + acc[1]) + (acc[2] + acc[3]);

        // per-j u, then logit = (u_j . usum) / sqrt(16)
        float lv[16];
        #pragma unroll
        for (int j = 0; j < 16; ++j) {
            U8 a; a.q = wpn[j * 16];
            f32x4 u = __builtin_amdgcn_mfma_f32_16x16x32_bf16(a.v, xf[j], zero4, 0, 0, 0);
            float p = u[0] * usum[0];
            p = fmaf(u[1], usum[1], p);
            p = fmaf(u[2], usum[2], p);
            p = fmaf(u[3], usum[3], p);
            p += __shfl_xor(p, 16);       // combine z-groups
            p += __shfl_xor(p, 32);
            lv[j] = p * 0.25f;
        }
        if (lane < 16) {
            float4* dst = reinterpret_cast<float4*>(&sL[l16 * SLS + n * 16]);
            dst[0] = make_float4(lv[0],  lv[1],  lv[2],  lv[3]);
            dst[1] = make_float4(lv[4],  lv[5],  lv[6],  lv[7]);
            dst[2] = make_float4(lv[8],  lv[9],  lv[10], lv[11]);
            dst[3] = make_float4(lv[12], lv[13], lv[14], lv[15]);
        }
    }
    __syncthreads();

    // ---------------- softmax over n (+ bias), one (b,j) per thread ----------------
    {
        const int sb = t >> 4, sj = t & 15;
        float l[32];
        #pragma unroll
        for (int n = 0; n < 32; ++n) l[n] = sL[sb * SLS + n * 16 + sj];
        float m = l[0];
        #pragma unroll
        for (int n = 1; n < 32; ++n) m = fmaxf(m, l[n]);
        float Z = 0.f;
        #pragma unroll
        for (int n = 0; n < 32; ++n) { l[n] = __expf(l[n] - m); Z += l[n]; }
        const float inv = 1.0f / Z;
        #pragma unroll
        for (int n = 0; n < 32; ++n)
            sL[sb * SLS + n * 16 + sj] = fmaf(l[n], inv, sBias[n * 16 + sj]);
    }
    __syncthreads();

    // ---------------- pass 2: s[b,n,z] = sum_j c_j * u_j ----------------
    #pragma unroll 1
    for (int q = 0; q < 8; ++q) {
        const int n = wv * 8 + q;
        const uint4* wpn = Wp + n * 256 + l16;
        const float4* cp = reinterpret_cast<const float4*>(&sL[l16 * SLS + n * 16]);
        const float4 c0 = cp[0], c1 = cp[1], c2 = cp[2], c3 = cp[3];
        const float cj[16] = {c0.x,c0.y,c0.z,c0.w, c1.x,c1.y,c1.z,c1.w,
                              c2.x,c2.y,c2.z,c2.w, c3.x,c3.y,c3.z,c3.w};
        float s0 = 0.f, s1 = 0.f, s2 = 0.f, s3 = 0.f;
        #pragma unroll
        for (int j = 0; j < 16; ++j) {
            U8 a; a.q = wpn[j * 16];
            f32x4 u = __builtin_amdgcn_mfma_f32_16x16x32_bf16(a.v, xf[j], zero4, 0, 0, 0);
            s0 = fmaf(cj[j], u[0], s0);
            s1 = fmaf(cj[j], u[1], s1);
            s2 = fmaf(cj[j], u[2], s2);
            s3 = fmaf(cj[j], u[3], s3);
        }
        // lanes (l16, zg) -> Out[bb+l16][n][zg*4 .. zg*4+3]; 64B lines fully covered
        float4* op = reinterpret_cast<float4*>(Out + (bb + l16) * 512 + n * 16 + zg * 4);
        *op = make_float4(s0, s1, s2, s3);
    }
}

extern "C" void kernel_launch(void* const* d_in, const int* in_sizes, int n_in,
                              void* d_out, int out_size, void* d_ws, size_t ws_size,
                              hipStream_t stream) {
    const float* X  = (const float*)d_in[0];   // (16384, 16, 8) fp32
    const float* W  = (const float*)d_in[1];   // (32, 16, 8, 16) fp32
    const float* Bi = (const float*)d_in[2];   // (32, 16, 1) fp32
    float* Out = (float*)d_out;                // (16384, 32, 16) fp32

    uint4* Wp = (uint4*)d_ws;                  // 128 KiB packed W fragments
    prepack_W<<<32, 256, 0, stream>>>(W, Wp);
    caps_mfma<<<B_TOT / TBB, NTH, 0, stream>>>(X, Wp, Bi, Out);
}

// Round 4
// 113.793 us; speedup vs baseline: 3.6415x; 1.0378x over previous
//
#include <hip/hip_runtime.h>

// Problem constants (fixed by the reference)
#define B_TOT 16384
#define TBB   16        // batch rows per block
#define NTH   256       // 4 waves; wave wv handles n in [8wv, 8wv+8)
#define SLS   524       // f32 stride of sL row (as verified in R2)

typedef short bf16x8 __attribute__((ext_vector_type(8)));
typedef float f32x4  __attribute__((ext_vector_type(4)));
union U4 { bf16x8 v; uint4 q; };

__device__ __forceinline__ unsigned f2bf(float f) {
    unsigned u = __float_as_uint(f);
    return (u + 0x7fffu + ((u >> 16) & 1u)) >> 16;   // RNE
}

__device__ __forceinline__ uint4 packrow(const float* src) {   // 8 W elems, i-stride 16
    uint4 o;
    o.x = f2bf(src[0])  | (f2bf(src[16])  << 16);
    o.y = f2bf(src[32]) | (f2bf(src[48])  << 16);
    o.z = f2bf(src[64]) | (f2bf(src[80])  << 16);
    o.w = f2bf(src[96]) | (f2bf(src[112]) << 16);
    return o;
}

// Wp layout (uint4 units):
//  [0, 8192):      Wk[n][s][lane]  — K=32 fully packed A-frag: lane(q=l>>4, z=l&15)
//                  holds W[n][4s+q][i=0..7][z]  (usum: 4 chained MFMAs cover all 16 j)
//  [8192, 40960):  Waj[n][j][lane] — per-j A-frag: octet q==(j&3) holds W[n][j][:][z],
//                  other octets ZERO (j-isolation: zeros kill the other octets' products
//                  regardless of B content; robust to the octet<->k convention since A
//                  and B share the same (quarter,elem)->k mapping)
__global__ void prepack(const float* __restrict__ W, uint4* __restrict__ Wp)
{
    const int t = blockIdx.x * 256 + threadIdx.x;   // 40960 threads
    if (t < 8192) {
        const int lane = t & 63, s = (t >> 6) & 3, n = t >> 8;
        const int q = lane >> 4, z = lane & 15;
        const int j = 4 * s + q;
        Wp[t] = packrow(W + (size_t)(n * 16 + j) * 128 + z);
    } else {
        const int u = t - 8192;
        const int lane = u & 63, j = (u >> 6) & 15, n = u >> 10;
        const int q = lane >> 4, z = lane & 15;
        uint4 o = make_uint4(0u, 0u, 0u, 0u);
        if (q == (j & 3))
            o = packrow(W + (size_t)(n * 16 + j) * 128 + z);
        Wp[t] = o;
    }
}

// D-mapping (m89-verified, identical to the PASSING R2 kernel):
//   col = lane&15 = b, row = 4*(lane>>4) + reg = z.
__global__ __launch_bounds__(NTH, 4)
void caps(const float* __restrict__ X, const uint4* __restrict__ Wp,
          const float* __restrict__ Bias, float* __restrict__ Out)
{
    __shared__ __align__(16) float sL[TBB * SLS];   // logits -> c+bias, f32 (33.5 KB)
    __shared__ float sBias[512];

    const int t    = threadIdx.x;
    const int lane = t & 63;
    const int wv   = t >> 6;          // 0..3
    const int b16  = lane & 15;       // D col = batch row
    const int q    = lane >> 4;       // lane quarter = K-octet = z-row group
    const long bb  = (long)blockIdx.x * TBB;

    sBias[t]       = Bias[t];
    sBias[t + 256] = Bias[t + 256];

    // x B-frags, K=32 packed (4 j per frag): frag s, lane (q,b16) = x[b16][4s+q][0..7]
    uint4 xq[4];
    #pragma unroll
    for (int s = 0; s < 4; ++s) {
        const float* xs = X + (bb + b16) * 128 + (4 * s + q) * 8;
        float4 a = *reinterpret_cast<const float4*>(xs);
        float4 c = *reinterpret_cast<const float4*>(xs + 4);
        uint4 o;
        o.x = f2bf(a.x) | (f2bf(a.y) << 16);
        o.y = f2bf(a.z) | (f2bf(a.w) << 16);
        o.z = f2bf(c.x) | (f2bf(c.y) << 16);
        o.w = f2bf(c.z) | (f2bf(c.w) << 16);
        xq[s] = o;
    }

    const f32x4 zero4 = {0.f, 0.f, 0.f, 0.f};

    // ---------------- pass 1: logits for this wave's 8 n ----------------
    #pragma unroll 1
    for (int nq = 0; nq < 8; ++nq) {
        const int n = wv * 8 + nq;
        const uint4* wk = Wp + n * 256 + lane;

        f32x4 usum = zero4;                        // usum[b,z]: 4 chained MFMAs
        #pragma unroll
        for (int s = 0; s < 4; ++s) {
            U4 a;  a.q  = wk[s * 64];
            U4 xb; xb.q = xq[s];
            usum = __builtin_amdgcn_mfma_f32_16x16x32_bf16(a.v, xb.v, usum, 0, 0, 0);
        }

        const uint4* wj = Wp + 8192 + n * 1024 + lane;
        float lv[16];
        #pragma unroll
        for (int j = 0; j < 16; ++j) {             // 16 independent per-j MFMAs
            U4 a;  a.q  = wj[j * 64];              // octet-masked W_j
            U4 xb; xb.q = xq[j >> 2];              // full B; zeros in A isolate j
            f32x4 u = __builtin_amdgcn_mfma_f32_16x16x32_bf16(a.v, xb.v, zero4, 0, 0, 0);
            float p = u[0] * usum[0];
            p = fmaf(u[1], usum[1], p);
            p = fmaf(u[2], usum[2], p);
            p = fmaf(u[3], usum[3], p);
            p += __shfl_xor(p, 16);                // sum the 4 z-quarters
            p += __shfl_xor(p, 32);
            lv[j] = p * 0.25f;                     // /sqrt(D)
        }
        if (lane < 16) {
            float4* dst = reinterpret_cast<float4*>(&sL[b16 * SLS + n * 16]);
            dst[0] = make_float4(lv[0],  lv[1],  lv[2],  lv[3]);
            dst[1] = make_float4(lv[4],  lv[5],  lv[6],  lv[7]);
            dst[2] = make_float4(lv[8],  lv[9],  lv[10], lv[11]);
            dst[3] = make_float4(lv[12], lv[13], lv[14], lv[15]);
        }
    }
    __syncthreads();

    // ---------------- softmax over n (+ bias), one (b,j) per thread ----------------
    {
        const int sb = t >> 4, sj = t & 15;
        float l[32];
        #pragma unroll
        for (int n = 0; n < 32; ++n) l[n] = sL[sb * SLS + n * 16 + sj];
        float m = l[0];
        #pragma unroll
        for (int n = 1; n < 32; ++n) m = fmaxf(m, l[n]);
        float Z = 0.f;
        #pragma unroll
        for (int n = 0; n < 32; ++n) { l[n] = __expf(l[n] - m); Z += l[n]; }
        const float inv = 1.0f / Z;
        #pragma unroll
        for (int n = 0; n < 32; ++n)
            sL[sb * SLS + n * 16 + sj] = fmaf(l[n], inv, sBias[n * 16 + sj]);
    }
    __syncthreads();

    // ---------------- pass 2: s[b,n,z] = sum_j c_j * u_j ----------------
    #pragma unroll 2
    for (int nq = 0; nq < 8; ++nq) {
        const int n = wv * 8 + nq;
        const uint4* wj = Wp + 8192 + n * 1024 + lane;
        float s0 = 0.f, s1 = 0.f, s2 = 0.f, s3 = 0.f;
        #pragma unroll
        for (int jp = 0; jp < 8; ++jp) {
            float2 c2 = *reinterpret_cast<const float2*>(&sL[b16 * SLS + n * 16 + 2 * jp]);
            U4 a0; a0.q = wj[(2 * jp) * 64];
            U4 a1; a1.q = wj[(2 * jp + 1) * 64];
            U4 x0; x0.q = xq[jp >> 1];             // (2jp)>>2 == (2jp+1)>>2 == jp>>1
            f32x4 u0 = __builtin_amdgcn_mfma_f32_16x16x32_bf16(a0.v, x0.v, zero4, 0, 0, 0);
            f32x4 u1 = __builtin_amdgcn_mfma_f32_16x16x32_bf16(a1.v, x0.v, zero4, 0, 0, 0);
            s0 = fmaf(c2.x, u0[0], s0); s0 = fmaf(c2.y, u1[0], s0);
            s1 = fmaf(c2.x, u0[1], s1); s1 = fmaf(c2.y, u1[1], s1);
            s2 = fmaf(c2.x, u0[2], s2); s2 = fmaf(c2.y, u1[2], s2);
            s3 = fmaf(c2.x, u0[3], s3); s3 = fmaf(c2.y, u1[3], s3);
        }
        // lane (b16, q) -> Out[bb+b16][n][4q .. 4q+3]  (same epilogue as verified R2)
        float4* op = reinterpret_cast<float4*>(Out + (bb + b16) * 512 + n * 16 + q * 4);
        *op = make_float4(s0, s1, s2, s3);
    }
}

extern "C" void kernel_launch(void* const* d_in, const int* in_sizes, int n_in,
                              void* d_out, int out_size, void* d_ws, size_t ws_size,
                              hipStream_t stream) {
    const float* X  = (const float*)d_in[0];   // (16384, 16, 8) fp32
    const float* W  = (const float*)d_in[1];   // (32, 16, 8, 16) fp32
    const float* Bi = (const float*)d_in[2];   // (32, 16, 1) fp32
    float* Out = (float*)d_out;                // (16384, 32, 16) fp32

    uint4* Wp = (uint4*)d_ws;                  // 640 KiB packed fragments
    prepack<<<160, 256, 0, stream>>>(W, Wp);
    caps<<<B_TOT / TBB, NTH, 0, stream>>>(X, Wp, Bi, Out);
}

// Round 5
// 101.707 us; speedup vs baseline: 4.0743x; 1.1188x over previous
//
#include <hip/hip_runtime.h>

// Problem constants (fixed by the reference)
#define B_TOT 16384
#define TBB   16        // batch rows per block
#define NTH   256       // 4 waves; wave wv handles n in [8wv, 8wv+8)
#define SLS   524       // f32 stride of sL row (verified R2/R4)

typedef short bf16x8 __attribute__((ext_vector_type(8)));
typedef float f32x4  __attribute__((ext_vector_type(4)));
union U4 { bf16x8 v; uint4 q; };

__device__ __forceinline__ unsigned f2bf(float f) {
    unsigned u = __float_as_uint(f);
    return (u + 0x7fffu + ((u >> 16) & 1u)) >> 16;   // RNE
}

__device__ __forceinline__ uint4 packrow(const float* src) {   // 8 W elems, i-stride 16
    uint4 o;
    o.x = f2bf(src[0])  | (f2bf(src[16])  << 16);
    o.y = f2bf(src[32]) | (f2bf(src[48])  << 16);
    o.z = f2bf(src[64]) | (f2bf(src[80])  << 16);
    o.w = f2bf(src[96]) | (f2bf(src[112]) << 16);
    return o;
}

// Wk[n][s][lane] (uint4): K=32 packed A-frag; lane (q=l>>4, z=l&15) holds
// W[n][4s+q][i=0..7][z]. Per-j fragments are derived IN REGISTERS by AND-masking
// lane-quarter q == (j&3) (bit-identical to R4's prepacked zero-octet frags).
__global__ void prepack(const float* __restrict__ W, uint4* __restrict__ Wp)
{
    const int t = blockIdx.x * 256 + threadIdx.x;   // 8192 threads
    const int lane = t & 63, s = (t >> 6) & 3, n = t >> 8;
    const int q = lane >> 4, z = lane & 15;
    Wp[t] = packrow(W + (size_t)(n * 16 + 4 * s + q) * 128 + z);
}

// D-mapping (m89-verified, identical to PASSING R4): col = lane&15 = b, row = 4q + reg = z.
__global__ __launch_bounds__(NTH, 4)
void caps(const float* __restrict__ X, const uint4* __restrict__ Wp,
          const float* __restrict__ Bias, float* __restrict__ Out)
{
    __shared__ __align__(16) float sL[TBB * SLS];   // logits -> c+bias, f32
    __shared__ float sBias[512];

    const int t    = threadIdx.x;
    const int lane = t & 63;
    const int wv   = t >> 6;          // 0..3
    const int b16  = lane & 15;       // D col = batch row
    const int q    = lane >> 4;       // lane quarter = K-octet = z-row group
    const long bb  = (long)blockIdx.x * TBB;

    sBias[t]       = Bias[t];
    sBias[t + 256] = Bias[t + 256];

    // per-octet lane masks: moct[c] = ~0 iff this lane's quarter q == c
    unsigned moct[4];
    #pragma unroll
    for (int c = 0; c < 4; ++c) moct[c] = (q == c) ? 0xffffffffu : 0u;

    // x B-frags, K=32 packed (4 j per frag): frag s, lane (q,b16) = x[b16][4s+q][0..7]
    uint4 xq[4];
    #pragma unroll
    for (int s = 0; s < 4; ++s) {
        const float* xs = X + (bb + b16) * 128 + (4 * s + q) * 8;
        float4 a = *reinterpret_cast<const float4*>(xs);
        float4 c = *reinterpret_cast<const float4*>(xs + 4);
        uint4 o;
        o.x = f2bf(a.x) | (f2bf(a.y) << 16);
        o.y = f2bf(a.z) | (f2bf(a.w) << 16);
        o.z = f2bf(c.x) | (f2bf(c.y) << 16);
        o.w = f2bf(c.z) | (f2bf(c.w) << 16);
        xq[s] = o;
    }

    const f32x4 zero4 = {0.f, 0.f, 0.f, 0.f};

    // masked per-j A-frag from the K=32 frag (4 v_and; bit-identical to R4 wj loads)
    auto maskA = [&](const uint4& wkf, int c) {
        U4 a;
        const unsigned m = moct[c];
        a.q.x = wkf.x & m; a.q.y = wkf.y & m;
        a.q.z = wkf.z & m; a.q.w = wkf.w & m;
        return a;
    };

    uint4 wk[4], wn[4];

    // ---------------- pass 1: logits for this wave's 8 n ----------------
    {
        const uint4* p0 = Wp + (wv * 8) * 256 + lane;
        wk[0] = p0[0]; wk[1] = p0[64]; wk[2] = p0[128]; wk[3] = p0[192];
    }
    #pragma unroll 1
    for (int nq = 0; nq < 8; ++nq) {
        const int n  = wv * 8 + nq;
        const int np = (nq < 7) ? n + 1 : n;            // prefetch next n's Wk
        const uint4* pn = Wp + np * 256 + lane;
        wn[0] = pn[0]; wn[1] = pn[64]; wn[2] = pn[128]; wn[3] = pn[192];

        f32x4 usum = zero4;                             // usum[b,z]: 4 chained MFMAs
        #pragma unroll
        for (int s = 0; s < 4; ++s) {
            U4 a;  a.q  = wk[s];
            U4 xb; xb.q = xq[s];
            usum = __builtin_amdgcn_mfma_f32_16x16x32_bf16(a.v, xb.v, usum, 0, 0, 0);
        }

        float lv[16];
        #pragma unroll
        for (int j = 0; j < 16; ++j) {                  // 16 per-j MFMAs, zero loads
            U4 a  = maskA(wk[j >> 2], j & 3);
            U4 xb; xb.q = xq[j >> 2];
            f32x4 u = __builtin_amdgcn_mfma_f32_16x16x32_bf16(a.v, xb.v, zero4, 0, 0, 0);
            float p = u[0] * usum[0];
            p = fmaf(u[1], usum[1], p);
            p = fmaf(u[2], usum[2], p);
            p = fmaf(u[3], usum[3], p);
            p += __shfl_xor(p, 16);                     // sum the 4 z-quarters
            p += __shfl_xor(p, 32);
            lv[j] = p * 0.25f;                          // /sqrt(D)
        }
        if (lane < 16) {
            float4* dst = reinterpret_cast<float4*>(&sL[b16 * SLS + n * 16]);
            dst[0] = make_float4(lv[0],  lv[1],  lv[2],  lv[3]);
            dst[1] = make_float4(lv[4],  lv[5],  lv[6],  lv[7]);
            dst[2] = make_float4(lv[8],  lv[9],  lv[10], lv[11]);
            dst[3] = make_float4(lv[12], lv[13], lv[14], lv[15]);
        }
        wk[0] = wn[0]; wk[1] = wn[1]; wk[2] = wn[2]; wk[3] = wn[3];
    }
    __syncthreads();

    // ---------------- softmax over n (+ bias), one (b,j) per thread ----------------
    {
        const int sb = t >> 4, sj = t & 15;
        float l[32];
        #pragma unroll
        for (int n = 0; n < 32; ++n) l[n] = sL[sb * SLS + n * 16 + sj];
        float m = l[0];
        #pragma unroll
        for (int n = 1; n < 32; ++n) m = fmaxf(m, l[n]);
        float Z = 0.f;
        #pragma unroll
        for (int n = 0; n < 32; ++n) { l[n] = __expf(l[n] - m); Z += l[n]; }
        const float inv = 1.0f / Z;
        #pragma unroll
        for (int n = 0; n < 32; ++n)
            sL[sb * SLS + n * 16 + sj] = fmaf(l[n], inv, sBias[n * 16 + sj]);
    }
    __syncthreads();

    // ---------------- pass 2: s[b,n,z] = sum_j c_j * u_j ----------------
    {
        const uint4* p0 = Wp + (wv * 8) * 256 + lane;
        wk[0] = p0[0]; wk[1] = p0[64]; wk[2] = p0[128]; wk[3] = p0[192];
    }
    #pragma unroll 1
    for (int nq = 0; nq < 8; ++nq) {
        const int n  = wv * 8 + nq;
        const int np = (nq < 7) ? n + 1 : n;
        const uint4* pn = Wp + np * 256 + lane;
        wn[0] = pn[0]; wn[1] = pn[64]; wn[2] = pn[128]; wn[3] = pn[192];

        float s0 = 0.f, s1 = 0.f, s2 = 0.f, s3 = 0.f;
        #pragma unroll
        for (int jp = 0; jp < 8; ++jp) {
            float2 c2 = *reinterpret_cast<const float2*>(&sL[b16 * SLS + n * 16 + 2 * jp]);
            U4 a0 = maskA(wk[jp >> 1], (2 * jp) & 3);
            U4 a1 = maskA(wk[jp >> 1], (2 * jp + 1) & 3);
            U4 x0; x0.q = xq[jp >> 1];                  // (2jp)>>2 == (2jp+1)>>2 == jp>>1
            f32x4 u0 = __builtin_amdgcn_mfma_f32_16x16x32_bf16(a0.v, x0.v, zero4, 0, 0, 0);
            f32x4 u1 = __builtin_amdgcn_mfma_f32_16x16x32_bf16(a1.v, x0.v, zero4, 0, 0, 0);
            s0 = fmaf(c2.x, u0[0], s0); s0 = fmaf(c2.y, u1[0], s0);
            s1 = fmaf(c2.x, u0[1], s1); s1 = fmaf(c2.y, u1[1], s1);
            s2 = fmaf(c2.x, u0[2], s2); s2 = fmaf(c2.y, u1[2], s2);
            s3 = fmaf(c2.x, u0[3], s3); s3 = fmaf(c2.y, u1[3], s3);
        }
        // lane (b16, q) -> Out[bb+b16][n][4q .. 4q+3]  (verified epilogue)
        float4* op = reinterpret_cast<float4*>(Out + (bb + b16) * 512 + n * 16 + q * 4);
        *op = make_float4(s0, s1, s2, s3);
        wk[0] = wn[0]; wk[1] = wn[1]; wk[2] = wn[2]; wk[3] = wn[3];
    }
}

extern "C" void kernel_launch(void* const* d_in, const int* in_sizes, int n_in,
                              void* d_out, int out_size, void* d_ws, size_t ws_size,
                              hipStream_t stream) {
    const float* X  = (const float*)d_in[0];   // (16384, 16, 8) fp32
    const float* W  = (const float*)d_in[1];   // (32, 16, 8, 16) fp32
    const float* Bi = (const float*)d_in[2];   // (32, 16, 1) fp32
    float* Out = (float*)d_out;                // (16384, 32, 16) fp32

    uint4* Wp = (uint4*)d_ws;                  // 128 KiB packed Wk fragments
    prepack<<<32, 256, 0, stream>>>(W, Wp);
    caps<<<B_TOT / TBB, NTH, 0, stream>>>(X, Wp, Bi, Out);
}